// Round 9
// baseline (237.248 us; speedup 1.0000x reference)
//
#include <hip/hip_runtime.h>
#include <hip/hip_fp16.h>

typedef _Float16 v8h __attribute__((ext_vector_type(8)));
typedef _Float16 v4h __attribute__((ext_vector_type(4)));
typedef float v4f __attribute__((ext_vector_type(4)));

#define MFMA_F16 __builtin_amdgcn_mfma_f32_16x16x32_f16
#define MFMA16_F16 __builtin_amdgcn_mfma_f32_16x16x16f16
#define EXP2F __builtin_amdgcn_exp2f

__device__ static inline void async_copy16(const void* g, void* l) {
  __builtin_amdgcn_global_load_lds(
      (const __attribute__((address_space(1))) void*)g,
      (__attribute__((address_space(3))) void*)l, 16, 0, 0);
}

// ---------------- flattened batched cast fp32 -> f16 (x8) -------------------
struct CastArgs {
  const float* src[10];
  _Float16* dst[10];
  int start[11];   // prefix offsets in v8-chunks; start[10] = total
  float scale[10];
};
__global__ void cast_all(CastArgs a) {
  const int g = blockIdx.x * 256 + threadIdx.x;
  if (g >= a.start[10]) return;
  int z = 0;
  #pragma unroll
  for (int i = 1; i < 10; ++i) if (g >= a.start[i]) z = i;
  const int i0 = g - a.start[z];
  const float sc = a.scale[z];
  const float* s = a.src[z] + (size_t)i0 * 8;
  const float4 f0 = *(const float4*)s;
  const float4 f1 = *(const float4*)(s + 4);
  v8h o = {(_Float16)(f0.x * sc), (_Float16)(f0.y * sc),
           (_Float16)(f0.z * sc), (_Float16)(f0.w * sc),
           (_Float16)(f1.x * sc), (_Float16)(f1.y * sc),
           (_Float16)(f1.z * sc), (_Float16)(f1.w * sc)};
  *(v8h*)(a.dst[z] + (size_t)i0 * 8) = o;
}

// ---------------- batched f16 GEMM: out_z = A_z @ W_z^T + bias --------------
// MT = M-tile (128 or 64). N-tile 128, BK=64, async staging, XOR-swizzled.
// mode: 0 = f16 row-major, 1 = f16 V-transpose [bh][dk][s'] (PV-permuted),
//       2 = f32 row-major.
struct GemmArgs {
  const _Float16* A1[4]; const _Float16* A2[4];
  const _Float16* W1[4]; const _Float16* W2[4];
  const float* b1[4];    const float* b2[4];
  void* out[4];
  float bscale[4];
  int K[4];
  int mode[4];
};

template <int MT>
__global__ __launch_bounds__(256) void gemm_mt(GemmArgs g) {
  constexpr int iA = MT / 32;          // A staging instructions per thread
  constexpr int NMT = MT / 32;         // m-subtiles per wave
  __shared__ _Float16 a_lds[MT * 64];
  __shared__ _Float16 w_lds[128 * 64];
  const int z = blockIdx.z;
  const int KK = g.K[z];
  const int tid = threadIdx.x;
  const int w = tid >> 6, lane = tid & 63, quad = lane >> 4, l16 = lane & 15;
  const int m0 = blockIdx.x * MT, n0 = blockIdx.y * 128;
  const int wm = (w >> 1) * (MT / 2), wn = (w & 1) * 64;

  size_t srcOff[4]; int ldsOff[4];
  #pragma unroll
  for (int i = 0; i < 4; ++i) {
    const int c = i * 256 + tid, row = c >> 3, slot = c & 7;
    srcOff[i] = (size_t)row * 768 + (size_t)((slot ^ (row & 7)) * 8);
    ldsOff[i] = (i * 256 + w * 64) * 8;
  }

  v4f acc[NMT][4] = {};

  for (int k0 = 0; k0 < KK; k0 += 64) {
    const _Float16* Asrc = (k0 < 768) ? g.A1[z] : g.A2[z];
    const _Float16* Wsrc = (k0 < 768) ? g.W1[z] : g.W2[z];
    const int kc = (k0 < 768) ? k0 : k0 - 768;
    __syncthreads();
    #pragma unroll
    for (int i = 0; i < 4; ++i) {
      if (i < iA)
        async_copy16(Asrc + (size_t)m0 * 768 + kc + srcOff[i], &a_lds[ldsOff[i]]);
      async_copy16(Wsrc + (size_t)n0 * 768 + kc + srcOff[i], &w_lds[ldsOff[i]]);
    }
    __syncthreads();

    #pragma unroll
    for (int kh = 0; kh < 2; ++kh) {
      v8h af[NMT], bf[4];
      #pragma unroll
      for (int mt = 0; mt < NMT; ++mt) {
        const int r = wm + mt * 16 + l16;
        af[mt] = *(const v8h*)&a_lds[r * 64 + (((kh * 4 + quad) ^ (r & 7)) * 8)];
      }
      #pragma unroll
      for (int nt = 0; nt < 4; ++nt) {
        const int r = wn + nt * 16 + l16;
        bf[nt] = *(const v8h*)&w_lds[r * 64 + (((kh * 4 + quad) ^ (r & 7)) * 8)];
      }
      #pragma unroll
      for (int mt = 0; mt < NMT; ++mt)
        #pragma unroll
        for (int nt = 0; nt < 4; ++nt)
          acc[mt][nt] = MFMA_F16(af[mt], bf[nt], acc[mt][nt], 0, 0, 0);
    }
  }

  const int mode = g.mode[z];
  #pragma unroll
  for (int nt = 0; nt < 4; ++nt) {
    const int col = n0 + wn + nt * 16 + l16;
    float bv = g.b1[z][col] * g.bscale[z];
    if (g.b2[z]) bv += g.b2[z][col];
    if (mode == 1) {
      // Vt[((b*12+h)*64+dk)*1024 + s'];  s = tile|q4|j -> s' = q4|tile|j
      _Float16* outp = (_Float16*)g.out[z];
      const int h = col >> 6, dk = col & 63;
      #pragma unroll
      for (int mt = 0; mt < NMT; ++mt) {
        const int row = m0 + wm + mt * 16 + quad * 4;
        const int b = row >> 10, s = row & 1023;
        const int sp = (s & ~31) | ((s & 12) << 1) | ((s & 16) >> 2);
        v4h pack = {(_Float16)(acc[mt][nt][0] + bv), (_Float16)(acc[mt][nt][1] + bv),
                    (_Float16)(acc[mt][nt][2] + bv), (_Float16)(acc[mt][nt][3] + bv)};
        *(v4h*)&outp[(size_t)((b * 12 + h) * 64 + dk) * 1024 + sp] = pack;
      }
    } else {
      #pragma unroll
      for (int mt = 0; mt < NMT; ++mt)
        #pragma unroll
        for (int r = 0; r < 4; ++r) {
          const int row = m0 + wm + mt * 16 + quad * 4 + r;
          const float v = acc[mt][nt][r] + bv;
          if (mode == 2) ((float*)g.out[z])[(size_t)row * 768 + col] = v;
          else ((_Float16*)g.out[z])[(size_t)row * 768 + col] = (_Float16)v;
        }
    }
  }
}

// ---------------- fused dual-time attention (transposed-score form) --------
// R6-measured structure (49 µs, MfmaUtil 35%, 0 conflicts): x32 scores,
// x16 PV + ones-trick row sums, 64-kv chunks, dbuf async staging.
__global__ __launch_bounds__(256) void attn(
    const _Float16* __restrict__ Q,
    const _Float16* __restrict__ KT0, const _Float16* __restrict__ KT1,
    const _Float16* __restrict__ Vt,   // [48*64][1024] permuted
    _Float16* __restrict__ X)          // [B*S,768]
{
  __shared__ _Float16 kt0[2][64 * 64];
  __shared__ _Float16 kt1[2][64 * 64];
  __shared__ _Float16 vt[2][64 * 64];

  const int tid = threadIdx.x;
  const int w = tid >> 6, lane = tid & 63, quad = lane >> 4, l16 = lane & 15;
  const int bh = blockIdx.y, b = bh / 12, h = bh % 12;
  const int q0 = blockIdx.x * 64;
  const size_t base = (size_t)b * 1024 * 768 + h * 64;

  const _Float16* KT0b = KT0 + base;
  const _Float16* KT1b = KT1 + base;
  const _Float16* Vtb = Vt + (size_t)bh * 64 * 1024;

  size_t ktOff[2], vOff[2]; int ldsOff[2];
  #pragma unroll
  for (int i = 0; i < 2; ++i) {
    const int c = i * 256 + w * 64 + lane, row = c >> 3, slot = c & 7;
    const int logical = slot ^ (row & 7);
    ktOff[i] = (size_t)row * 768 + (size_t)(logical * 8);
    vOff[i] = (size_t)row * 1024 + (size_t)(logical * 8);
    ldsOff[i] = c * 8;
  }
  auto stage = [&](int kv0, int buf) {
    #pragma unroll
    for (int i = 0; i < 2; ++i) {
      async_copy16(KT0b + (size_t)kv0 * 768 + ktOff[i], &kt0[buf][ldsOff[i]]);
      async_copy16(KT1b + (size_t)kv0 * 768 + ktOff[i], &kt1[buf][ldsOff[i]]);
      async_copy16(Vtb + (size_t)kv0 + vOff[i], &vt[buf][ldsOff[i]]);
    }
  };

  const _Float16* Qw = Q + base + (size_t)(q0 + w * 16) * 768;
  const v8h qf0 = *(const v8h*)(Qw + (size_t)l16 * 768 + quad * 8);
  const v8h qf1 = *(const v8h*)(Qw + (size_t)l16 * 768 + 32 + quad * 8);

  const _Float16 one = (_Float16)1.f;
  const v4h ones = {one, one, one, one};
  v4f o[2][4] = {};      // O^T tiles [t][dkt]
  v4f osum[2] = {};      // softmax denominators via ones-MFMA

  stage(0, 0);
  for (int cc = 0; cc < 16; ++cc) {
    __syncthreads();
    if (cc < 15) stage((cc + 1) * 64, (cc + 1) & 1);
    const _Float16* k0p = &kt0[cc & 1][0];
    const _Float16* k1p = &kt1[cc & 1][0];
    const _Float16* vp = &vt[cc & 1][0];

    // S^T tiles [t][kvt]: A = KT frag (m=kv), B = Q frag
    v4f s[2][4];
    #pragma unroll
    for (int kvt = 0; kvt < 4; ++kvt) {
      const int r = kvt * 16 + l16, rw = r & 7;
      const v8h k00 = *(const v8h*)&k0p[r * 64 + ((quad ^ rw) * 8)];
      const v8h k01 = *(const v8h*)&k0p[r * 64 + (((4 + quad) ^ rw) * 8)];
      const v8h k10 = *(const v8h*)&k1p[r * 64 + ((quad ^ rw) * 8)];
      const v8h k11 = *(const v8h*)&k1p[r * 64 + (((4 + quad) ^ rw) * 8)];
      s[0][kvt] = MFMA_F16(k00, qf0, v4f{}, 0, 0, 0);
      s[0][kvt] = MFMA_F16(k01, qf1, s[0][kvt], 0, 0, 0);
      s[1][kvt] = MFMA_F16(k10, qf0, v4f{}, 0, 0, 0);
      s[1][kvt] = MFMA_F16(k11, qf1, s[1][kvt], 0, 0, 0);
    }

    // P = exp2(s) (log2e pre-folded), pack to f16 B-frags, MFMA row-sums
    v4h pb[2][4];
    #pragma unroll
    for (int t = 0; t < 2; ++t)
      #pragma unroll
      for (int kvt = 0; kvt < 4; ++kvt) {
        pb[t][kvt] = v4h{(_Float16)EXP2F(s[t][kvt][0]),
                         (_Float16)EXP2F(s[t][kvt][1]),
                         (_Float16)EXP2F(s[t][kvt][2]),
                         (_Float16)EXP2F(s[t][kvt][3])};
        osum[t] = MFMA16_F16(ones, pb[t][kvt], osum[t], 0, 0, 0);
      }

    // PV: O^T[dkt] += V^T frag · P^T ; one b128 feeds two kv-tiles (perm layout)
    #pragma unroll
    for (int dkt = 0; dkt < 4; ++dkt) {
      const int row = dkt * 16 + l16, rw = row & 7;
      #pragma unroll
      for (int gph = 0; gph < 2; ++gph) {
        const int phys = (gph * 4 + quad) ^ rw;
        const v8h vv = *(const v8h*)&vp[row * 64 + phys * 8];
        const v4h lo = {vv[0], vv[1], vv[2], vv[3]};
        const v4h hi = {vv[4], vv[5], vv[6], vv[7]};
        #pragma unroll
        for (int t = 0; t < 2; ++t) {
          o[t][dkt] = MFMA16_F16(lo, pb[t][gph * 2], o[t][dkt], 0, 0, 0);
          o[t][dkt] = MFMA16_F16(hi, pb[t][gph * 2 + 1], o[t][dkt], 0, 0, 0);
        }
      }
    }
  }

  // every lane already holds the full denominators (ones-MFMA rows identical)
  const float i0 = 1.0f / osum[0][0], i1 = 1.0f / osum[1][0];

  // O^T: col=l16=q, row=quad*4+r=dk-within-tile -> packed v4h stores
  _Float16* Xw = X + base + (size_t)(q0 + w * 16 + l16) * 768;
  #pragma unroll
  for (int dkt = 0; dkt < 4; ++dkt) {
    v4h pack;
    #pragma unroll
    for (int r = 0; r < 4; ++r)
      pack[r] = (_Float16)(o[0][dkt][r] * i0 + o[1][dkt][r] * i1);
    *(v4h*)&Xw[dkt * 16 + quad * 4] = pack;
  }
}

extern "C" void kernel_launch(void* const* d_in, const int* in_sizes, int n_in,
                              void* d_out, int out_size, void* d_ws, size_t ws_size,
                              hipStream_t stream) {
  const float* query = (const float*)d_in[0];
  const float* key   = (const float*)d_in[1];
  const float* value = (const float*)d_in[2];
  const float* times = (const float*)d_in[3];
  const float* Wq = (const float*)d_in[4];  const float* bq = (const float*)d_in[5];
  const float* Wk = (const float*)d_in[6];  const float* bk = (const float*)d_in[7];
  const float* Wv = (const float*)d_in[8];  const float* bv = (const float*)d_in[9];
  const float* Wt = (const float*)d_in[10]; const float* bt = (const float*)d_in[11];
  const float* Wo = (const float*)d_in[12]; const float* bo = (const float*)d_in[13];
  float* out = (float*)d_out;

  const size_t NELEM = (size_t)4096 * 768;
  const size_t WELEM = (size_t)768 * 768;
  const float QSCALE = 0.125f * 1.4426950408889634f;  // 1/sqrt(64)*log2(e)

  char* ws = (char*)d_ws;
  size_t off = 0;
  auto alloc = [&](size_t bytes) {
    void* p = ws + off; off += (bytes + 255) & ~(size_t)255; return p;
  };
  _Float16* qh  = (_Float16*)alloc(NELEM * 2);  // casted query; later Xh
  _Float16* kh  = (_Float16*)alloc(NELEM * 2);
  _Float16* vh  = (_Float16*)alloc(NELEM * 2);
  _Float16* wqh = (_Float16*)alloc(WELEM * 2);
  _Float16* wkh = (_Float16*)alloc(WELEM * 2);
  _Float16* wvh = (_Float16*)alloc(WELEM * 2);
  _Float16* wth = (_Float16*)alloc(WELEM * 2);
  _Float16* woh = (_Float16*)alloc(WELEM * 2);
  _Float16* Qh  = (_Float16*)alloc(NELEM * 2);
  _Float16* KT0 = (_Float16*)alloc(NELEM * 2);
  _Float16* KT1 = (_Float16*)alloc(NELEM * 2);
  _Float16* Vt  = (_Float16*)alloc(NELEM * 2);
  _Float16* t0h = (_Float16*)d_out;      // dead before final fp32 write
  _Float16* t1h = t0h + NELEM;
  _Float16* Xh = qh;                     // overlay: query dead after proj

  // ---- 1. flattened batched cast ----
  CastArgs ca = {};
  const int nA8 = (int)(NELEM / 8), nW8 = (int)(WELEM / 8);
  const float* csrc[10] = {query, key, value, times, times + NELEM, Wq, Wk, Wv, Wt, Wo};
  _Float16* cdst[10] = {qh, kh, vh, t0h, t1h, wqh, wkh, wvh, wth, woh};
  int acc8 = 0;
  for (int i = 0; i < 10; ++i) {
    ca.src[i] = csrc[i]; ca.dst[i] = cdst[i];
    ca.start[i] = acc8;
    acc8 += (i < 5) ? nA8 : nW8;
    ca.scale[i] = (i == 5) ? QSCALE : 1.0f;
  }
  ca.start[10] = acc8;
  cast_all<<<dim3((acc8 + 255) / 256), 256, 0, stream>>>(ca);

  // ---- 2. batched projections: z = {KT0, KT1, Q, V} ----
  GemmArgs pa = {};
  pa.A1[0] = t0h; pa.A2[0] = kh; pa.W1[0] = wth; pa.W2[0] = wkh;
  pa.b1[0] = bt; pa.b2[0] = bk; pa.out[0] = KT0; pa.bscale[0] = 1.0f;
  pa.K[0] = 1536; pa.mode[0] = 0;
  pa.A1[1] = t1h; pa.A2[1] = kh; pa.W1[1] = wth; pa.W2[1] = wkh;
  pa.b1[1] = bt; pa.b2[1] = bk; pa.out[1] = KT1; pa.bscale[1] = 1.0f;
  pa.K[1] = 1536; pa.mode[1] = 0;
  pa.A1[2] = qh; pa.A2[2] = qh; pa.W1[2] = wqh; pa.W2[2] = wqh;
  pa.b1[2] = bq; pa.b2[2] = nullptr; pa.out[2] = Qh; pa.bscale[2] = QSCALE;
  pa.K[2] = 768; pa.mode[2] = 0;
  pa.A1[3] = vh; pa.A2[3] = vh; pa.W1[3] = wvh; pa.W2[3] = wvh;
  pa.b1[3] = bv; pa.b2[3] = nullptr; pa.out[3] = Vt; pa.bscale[3] = 1.0f;
  pa.K[3] = 768; pa.mode[3] = 1;
  gemm_mt<128><<<dim3(32, 6, 4), 256, 0, stream>>>(pa);

  // ---- 3. fused dual-time attention -> Xh ----
  attn<<<dim3(16, 48), 256, 0, stream>>>(Qh, KT0, KT1, Vt, Xh);

  // ---- 4. output projection -> d_out (fp32), 64-row tiles for 384 blocks ----
  GemmArgs oa = {};
  oa.A1[0] = Xh; oa.A2[0] = Xh; oa.W1[0] = woh; oa.W2[0] = woh;
  oa.b1[0] = bo; oa.b2[0] = nullptr; oa.out[0] = out; oa.bscale[0] = 1.0f;
  oa.K[0] = 768; oa.mode[0] = 2;
  gemm_mt<64><<<dim3(64, 6, 1), 256, 0, stream>>>(oa);
}

// Round 10
// 236.447 us; speedup vs baseline: 1.0034x; 1.0034x over previous
//
#include <hip/hip_runtime.h>
#include <hip/hip_fp16.h>

typedef _Float16 v8h __attribute__((ext_vector_type(8)));
typedef _Float16 v4h __attribute__((ext_vector_type(4)));
typedef float v4f __attribute__((ext_vector_type(4)));

#define MFMA_F16 __builtin_amdgcn_mfma_f32_16x16x32_f16
#define MFMA16_F16 __builtin_amdgcn_mfma_f32_16x16x16f16
#define EXP2F __builtin_amdgcn_exp2f

__device__ static inline void async_copy16(const void* g, void* l) {
  __builtin_amdgcn_global_load_lds(
      (const __attribute__((address_space(1))) void*)g,
      (__attribute__((address_space(3))) void*)l, 16, 0, 0);
}

// ---------------- flattened batched cast fp32 -> f16 (x8) -------------------
// slice 4 is special: dst = (f16)(src2[i] - src[4][i])  (times1 - times0)
struct CastArgs {
  const float* src[10];
  const float* src2;
  _Float16* dst[10];
  int start[11];   // prefix offsets in v8-chunks; start[10] = total
  float scale[10];
};
__global__ void cast_all(CastArgs a) {
  const int g = blockIdx.x * 256 + threadIdx.x;
  if (g >= a.start[10]) return;
  int z = 0;
  #pragma unroll
  for (int i = 1; i < 10; ++i) if (g >= a.start[i]) z = i;
  const int i0 = g - a.start[z];
  const float* s = a.src[z] + (size_t)i0 * 8;
  float4 f0 = *(const float4*)s;
  float4 f1 = *(const float4*)(s + 4);
  if (z == 4) {
    const float* s2 = a.src2 + (size_t)i0 * 8;
    const float4 g0 = *(const float4*)s2;
    const float4 g1 = *(const float4*)(s2 + 4);
    f0 = make_float4(g0.x - f0.x, g0.y - f0.y, g0.z - f0.z, g0.w - f0.w);
    f1 = make_float4(g1.x - f1.x, g1.y - f1.y, g1.z - f1.z, g1.w - f1.w);
  }
  const float sc = a.scale[z];
  v8h o = {(_Float16)(f0.x * sc), (_Float16)(f0.y * sc),
           (_Float16)(f0.z * sc), (_Float16)(f0.w * sc),
           (_Float16)(f1.x * sc), (_Float16)(f1.y * sc),
           (_Float16)(f1.z * sc), (_Float16)(f1.w * sc)};
  *(v8h*)(a.dst[z] + (size_t)i0 * 8) = o;
}

// ---------------- batched f16 GEMM: out_z = A_z @ W_z^T + bias --------------
// MT = M-tile (128 or 64). N-tile 128, BK=64, async staging, XOR-swizzled.
// mode: 0 = f16 row-major, 1 = f16 V-transpose [bh][dk][s'] (PV-permuted),
//       2 = f32 row-major.
struct GemmArgs {
  const _Float16* A1[4]; const _Float16* A2[4];
  const _Float16* W1[4]; const _Float16* W2[4];
  const float* b1[4];    const float* b2[4];
  void* out[4];
  float bscale[4];
  int K[4];
  int mode[4];
};

template <int MT>
__global__ __launch_bounds__(256) void gemm_mt(GemmArgs g) {
  constexpr int iA = MT / 32;          // A staging instructions per thread
  constexpr int NMT = MT / 32;         // m-subtiles per wave
  __shared__ _Float16 a_lds[MT * 64];
  __shared__ _Float16 w_lds[128 * 64];
  const int z = blockIdx.z;
  const int KK = g.K[z];
  const int tid = threadIdx.x;
  const int w = tid >> 6, lane = tid & 63, quad = lane >> 4, l16 = lane & 15;
  const int m0 = blockIdx.x * MT, n0 = blockIdx.y * 128;
  const int wm = (w >> 1) * (MT / 2), wn = (w & 1) * 64;

  size_t srcOff[4]; int ldsOff[4];
  #pragma unroll
  for (int i = 0; i < 4; ++i) {
    const int c = i * 256 + tid, row = c >> 3, slot = c & 7;
    srcOff[i] = (size_t)row * 768 + (size_t)((slot ^ (row & 7)) * 8);
    ldsOff[i] = (i * 256 + w * 64) * 8;
  }

  v4f acc[NMT][4] = {};

  for (int k0 = 0; k0 < KK; k0 += 64) {
    const _Float16* Asrc = (k0 < 768) ? g.A1[z] : g.A2[z];
    const _Float16* Wsrc = (k0 < 768) ? g.W1[z] : g.W2[z];
    const int kc = (k0 < 768) ? k0 : k0 - 768;
    __syncthreads();
    #pragma unroll
    for (int i = 0; i < 4; ++i) {
      if (i < iA)
        async_copy16(Asrc + (size_t)m0 * 768 + kc + srcOff[i], &a_lds[ldsOff[i]]);
      async_copy16(Wsrc + (size_t)n0 * 768 + kc + srcOff[i], &w_lds[ldsOff[i]]);
    }
    __syncthreads();

    #pragma unroll
    for (int kh = 0; kh < 2; ++kh) {
      v8h af[NMT], bf[4];
      #pragma unroll
      for (int mt = 0; mt < NMT; ++mt) {
        const int r = wm + mt * 16 + l16;
        af[mt] = *(const v8h*)&a_lds[r * 64 + (((kh * 4 + quad) ^ (r & 7)) * 8)];
      }
      #pragma unroll
      for (int nt = 0; nt < 4; ++nt) {
        const int r = wn + nt * 16 + l16;
        bf[nt] = *(const v8h*)&w_lds[r * 64 + (((kh * 4 + quad) ^ (r & 7)) * 8)];
      }
      #pragma unroll
      for (int mt = 0; mt < NMT; ++mt)
        #pragma unroll
        for (int nt = 0; nt < 4; ++nt)
          acc[mt][nt] = MFMA_F16(af[mt], bf[nt], acc[mt][nt], 0, 0, 0);
    }
  }

  const int mode = g.mode[z];
  #pragma unroll
  for (int nt = 0; nt < 4; ++nt) {
    const int col = n0 + wn + nt * 16 + l16;
    float bv = g.b1[z][col] * g.bscale[z];
    if (g.b2[z]) bv += g.b2[z][col];
    if (mode == 1) {
      // Vt[((b*12+h)*64+dk)*1024 + s'];  s = tile|q4|j -> s' = q4|tile|j
      _Float16* outp = (_Float16*)g.out[z];
      const int h = col >> 6, dk = col & 63;
      #pragma unroll
      for (int mt = 0; mt < NMT; ++mt) {
        const int row = m0 + wm + mt * 16 + quad * 4;
        const int b = row >> 10, s = row & 1023;
        const int sp = (s & ~31) | ((s & 12) << 1) | ((s & 16) >> 2);
        v4h pack = {(_Float16)(acc[mt][nt][0] + bv), (_Float16)(acc[mt][nt][1] + bv),
                    (_Float16)(acc[mt][nt][2] + bv), (_Float16)(acc[mt][nt][3] + bv)};
        *(v4h*)&outp[(size_t)((b * 12 + h) * 64 + dk) * 1024 + sp] = pack;
      }
    } else {
      #pragma unroll
      for (int mt = 0; mt < NMT; ++mt)
        #pragma unroll
        for (int r = 0; r < 4; ++r) {
          const int row = m0 + wm + mt * 16 + quad * 4 + r;
          const float v = acc[mt][nt][r] + bv;
          if (mode == 2) ((float*)g.out[z])[(size_t)row * 768 + col] = v;
          else ((_Float16*)g.out[z])[(size_t)row * 768 + col] = (_Float16)v;
        }
    }
  }
}

// ---------------- fused dual-time attention (transposed-score form) --------
// R6-measured structure (49 µs, MfmaUtil 37%, 0 conflicts), with the
// linearity trick: S1 = S0 + Q·D^T, D = (times1-times0)@Wt^T. Same MFMA
// count per chunk (s1 accumulates from C=s0).
__global__ __launch_bounds__(256) void attn(
    const _Float16* __restrict__ Q,
    const _Float16* __restrict__ KT0, const _Float16* __restrict__ D,
    const _Float16* __restrict__ Vt,   // [48*64][1024] permuted
    _Float16* __restrict__ X)          // [B*S,768]
{
  __shared__ _Float16 ktl[2][64 * 64];
  __shared__ _Float16 dl[2][64 * 64];
  __shared__ _Float16 vt[2][64 * 64];

  const int tid = threadIdx.x;
  const int w = tid >> 6, lane = tid & 63, quad = lane >> 4, l16 = lane & 15;
  const int bh = blockIdx.y, b = bh / 12, h = bh % 12;
  const int q0 = blockIdx.x * 64;
  const size_t base = (size_t)b * 1024 * 768 + h * 64;

  const _Float16* KTb = KT0 + base;
  const _Float16* Db = D + base;
  const _Float16* Vtb = Vt + (size_t)bh * 64 * 1024;

  size_t ktOff[2], vOff[2]; int ldsOff[2];
  #pragma unroll
  for (int i = 0; i < 2; ++i) {
    const int c = i * 256 + w * 64 + lane, row = c >> 3, slot = c & 7;
    const int logical = slot ^ (row & 7);
    ktOff[i] = (size_t)row * 768 + (size_t)(logical * 8);
    vOff[i] = (size_t)row * 1024 + (size_t)(logical * 8);
    ldsOff[i] = c * 8;
  }
  auto stage = [&](int kv0, int buf) {
    #pragma unroll
    for (int i = 0; i < 2; ++i) {
      async_copy16(KTb + (size_t)kv0 * 768 + ktOff[i], &ktl[buf][ldsOff[i]]);
      async_copy16(Db + (size_t)kv0 * 768 + ktOff[i], &dl[buf][ldsOff[i]]);
      async_copy16(Vtb + (size_t)kv0 + vOff[i], &vt[buf][ldsOff[i]]);
    }
  };

  const _Float16* Qw = Q + base + (size_t)(q0 + w * 16) * 768;
  const v8h qf0 = *(const v8h*)(Qw + (size_t)l16 * 768 + quad * 8);
  const v8h qf1 = *(const v8h*)(Qw + (size_t)l16 * 768 + 32 + quad * 8);

  const _Float16 one = (_Float16)1.f;
  const v4h ones = {one, one, one, one};
  v4f o[2][4] = {};      // O^T tiles [t][dkt]
  v4f osum[2] = {};      // softmax denominators via ones-MFMA

  stage(0, 0);
  for (int cc = 0; cc < 16; ++cc) {
    __syncthreads();
    if (cc < 15) stage((cc + 1) * 64, (cc + 1) & 1);
    const _Float16* k0p = &ktl[cc & 1][0];
    const _Float16* dp = &dl[cc & 1][0];
    const _Float16* vp = &vt[cc & 1][0];

    // S^T tiles: s0 = KT0·Q^T;  s1 = s0 + D·Q^T (MFMA C-chaining)
    v4f s[2][4];
    #pragma unroll
    for (int kvt = 0; kvt < 4; ++kvt) {
      const int r = kvt * 16 + l16, rw = r & 7;
      const v8h k00 = *(const v8h*)&k0p[r * 64 + ((quad ^ rw) * 8)];
      const v8h k01 = *(const v8h*)&k0p[r * 64 + (((4 + quad) ^ rw) * 8)];
      const v8h d0 = *(const v8h*)&dp[r * 64 + ((quad ^ rw) * 8)];
      const v8h d1 = *(const v8h*)&dp[r * 64 + (((4 + quad) ^ rw) * 8)];
      s[0][kvt] = MFMA_F16(k00, qf0, v4f{}, 0, 0, 0);
      s[0][kvt] = MFMA_F16(k01, qf1, s[0][kvt], 0, 0, 0);
      s[1][kvt] = MFMA_F16(d0, qf0, s[0][kvt], 0, 0, 0);
      s[1][kvt] = MFMA_F16(d1, qf1, s[1][kvt], 0, 0, 0);
    }

    // P = exp2(s) (log2e pre-folded), pack to f16 B-frags, MFMA row-sums
    v4h pb[2][4];
    #pragma unroll
    for (int t = 0; t < 2; ++t)
      #pragma unroll
      for (int kvt = 0; kvt < 4; ++kvt) {
        pb[t][kvt] = v4h{(_Float16)EXP2F(s[t][kvt][0]),
                         (_Float16)EXP2F(s[t][kvt][1]),
                         (_Float16)EXP2F(s[t][kvt][2]),
                         (_Float16)EXP2F(s[t][kvt][3])};
        osum[t] = MFMA16_F16(ones, pb[t][kvt], osum[t], 0, 0, 0);
      }

    // PV: O^T[dkt] += V^T frag · P^T ; one b128 feeds two kv-tiles (perm layout)
    #pragma unroll
    for (int dkt = 0; dkt < 4; ++dkt) {
      const int row = dkt * 16 + l16, rw = row & 7;
      #pragma unroll
      for (int gph = 0; gph < 2; ++gph) {
        const int phys = (gph * 4 + quad) ^ rw;
        const v8h vv = *(const v8h*)&vp[row * 64 + phys * 8];
        const v4h lo = {vv[0], vv[1], vv[2], vv[3]};
        const v4h hi = {vv[4], vv[5], vv[6], vv[7]};
        #pragma unroll
        for (int t = 0; t < 2; ++t) {
          o[t][dkt] = MFMA16_F16(lo, pb[t][gph * 2], o[t][dkt], 0, 0, 0);
          o[t][dkt] = MFMA16_F16(hi, pb[t][gph * 2 + 1], o[t][dkt], 0, 0, 0);
        }
      }
    }
  }

  // every lane already holds the full denominators (ones-MFMA rows identical)
  const float i0 = 1.0f / osum[0][0], i1 = 1.0f / osum[1][0];

  // O^T: col=l16=q, row=quad*4+r=dk-within-tile -> packed v4h stores
  _Float16* Xw = X + base + (size_t)(q0 + w * 16 + l16) * 768;
  #pragma unroll
  for (int dkt = 0; dkt < 4; ++dkt) {
    v4h pack;
    #pragma unroll
    for (int r = 0; r < 4; ++r)
      pack[r] = (_Float16)(o[0][dkt][r] * i0 + o[1][dkt][r] * i1);
    *(v4h*)&Xw[dkt * 16 + quad * 4] = pack;
  }
}

extern "C" void kernel_launch(void* const* d_in, const int* in_sizes, int n_in,
                              void* d_out, int out_size, void* d_ws, size_t ws_size,
                              hipStream_t stream) {
  const float* query = (const float*)d_in[0];
  const float* key   = (const float*)d_in[1];
  const float* value = (const float*)d_in[2];
  const float* times = (const float*)d_in[3];
  const float* Wq = (const float*)d_in[4];  const float* bq = (const float*)d_in[5];
  const float* Wk = (const float*)d_in[6];  const float* bk = (const float*)d_in[7];
  const float* Wv = (const float*)d_in[8];  const float* bv = (const float*)d_in[9];
  const float* Wt = (const float*)d_in[10]; const float* bt = (const float*)d_in[11];
  const float* Wo = (const float*)d_in[12]; const float* bo = (const float*)d_in[13];
  float* out = (float*)d_out;

  const size_t NELEM = (size_t)4096 * 768;
  const size_t WELEM = (size_t)768 * 768;
  const float QSCALE = 0.125f * 1.4426950408889634f;  // 1/sqrt(64)*log2(e)

  char* ws = (char*)d_ws;
  size_t off = 0;
  auto alloc = [&](size_t bytes) {
    void* p = ws + off; off += (bytes + 255) & ~(size_t)255; return p;
  };
  _Float16* qh  = (_Float16*)alloc(NELEM * 2);  // casted query; later Xh
  _Float16* kh  = (_Float16*)alloc(NELEM * 2);
  _Float16* vh  = (_Float16*)alloc(NELEM * 2);
  _Float16* wqh = (_Float16*)alloc(WELEM * 2);
  _Float16* wkh = (_Float16*)alloc(WELEM * 2);
  _Float16* wvh = (_Float16*)alloc(WELEM * 2);
  _Float16* wth = (_Float16*)alloc(WELEM * 2);
  _Float16* woh = (_Float16*)alloc(WELEM * 2);
  _Float16* Qh  = (_Float16*)alloc(NELEM * 2);
  _Float16* KT0 = (_Float16*)alloc(NELEM * 2);
  _Float16* Dh  = (_Float16*)alloc(NELEM * 2);
  _Float16* Vt  = (_Float16*)alloc(NELEM * 2);
  _Float16* t0h = (_Float16*)d_out;      // d_out overlay: dead before final write
  _Float16* difh = t0h + NELEM;          // (times1-times0) f16
  _Float16* Xh = qh;                     // overlay: query dead after proj

  // ---- 1. flattened batched cast (slice 4 = times1 - times0) ----
  CastArgs ca = {};
  const int nA8 = (int)(NELEM / 8), nW8 = (int)(WELEM / 8);
  const float* csrc[10] = {query, key, value, times, times, Wq, Wk, Wv, Wt, Wo};
  _Float16* cdst[10] = {qh, kh, vh, t0h, difh, wqh, wkh, wvh, wth, woh};
  int acc8 = 0;
  for (int i = 0; i < 10; ++i) {
    ca.src[i] = csrc[i]; ca.dst[i] = cdst[i];
    ca.start[i] = acc8;
    acc8 += (i < 5) ? nA8 : nW8;
    ca.scale[i] = (i == 5) ? QSCALE : 1.0f;
  }
  ca.start[10] = acc8;
  ca.src2 = times + NELEM;
  cast_all<<<dim3((acc8 + 255) / 256), 256, 0, stream>>>(ca);

  // ---- 2. batched projections: z = {KT0 (K=1536), D, Q, V} ----
  GemmArgs pa = {};
  pa.A1[0] = t0h; pa.A2[0] = kh; pa.W1[0] = wth; pa.W2[0] = wkh;
  pa.b1[0] = bt; pa.b2[0] = bk; pa.out[0] = KT0; pa.bscale[0] = 1.0f;
  pa.K[0] = 1536; pa.mode[0] = 0;
  pa.A1[1] = difh; pa.A2[1] = difh; pa.W1[1] = wth; pa.W2[1] = wth;
  pa.b1[1] = bt; pa.b2[1] = nullptr; pa.out[1] = Dh; pa.bscale[1] = 0.0f;  // bias cancels
  pa.K[1] = 768; pa.mode[1] = 0;
  pa.A1[2] = qh; pa.A2[2] = qh; pa.W1[2] = wqh; pa.W2[2] = wqh;
  pa.b1[2] = bq; pa.b2[2] = nullptr; pa.out[2] = Qh; pa.bscale[2] = QSCALE;
  pa.K[2] = 768; pa.mode[2] = 0;
  pa.A1[3] = vh; pa.A2[3] = vh; pa.W1[3] = wvh; pa.W2[3] = wvh;
  pa.b1[3] = bv; pa.b2[3] = nullptr; pa.out[3] = Vt; pa.bscale[3] = 1.0f;
  pa.K[3] = 768; pa.mode[3] = 1;
  gemm_mt<128><<<dim3(32, 6, 4), 256, 0, stream>>>(pa);

  // ---- 3. fused dual-time attention -> Xh ----
  attn<<<dim3(16, 48), 256, 0, stream>>>(Qh, KT0, Dh, Vt, Xh);

  // ---- 4. output projection -> d_out (fp32), 64-row tiles for 384 blocks ----
  GemmArgs oa = {};
  oa.A1[0] = Xh; oa.A2[0] = Xh; oa.W1[0] = woh; oa.W2[0] = woh;
  oa.b1[0] = bo; oa.b2[0] = nullptr; oa.out[0] = out; oa.bscale[0] = 1.0f;
  oa.K[0] = 768; oa.mode[0] = 2;
  gemm_mt<64><<<dim3(64, 6, 1), 256, 0, stream>>>(oa);
}